// Round 6
// baseline (248.960 us; speedup 1.0000x reference)
//
#include <hip/hip_runtime.h>
#include <stdint.h>

// Problem constants (B,T,J,D) = (64, 2048, 128, 256)
#define Bb 64
#define Tt 2048
#define Jj 128
#define Dd 256

// R11 structure (R10 + DRAM-burst theory; R10 post-mortem: depth-6 prefetch
// NEUTRAL (-2.3 us = noise) -> latency already covered; kernel est ~75 us vs
// ~35 us traffic floor; suspect = strided column-walk H pattern (16 rows x
// 128 B at 1 KB stride per step) under-utilizing DRAM row buffers):
//  - Depth-8 H prefetch = FULL m-tile in registers (64 VGPR). Prologue
//    issues all 16 loads back-to-back -> each of the wave's 16 rows is
//    covered 1 KB-contiguously within one burst (DRAM-friendly); mt=1
//    refilled one pair/step during mt=0 (8-step lookahead).
//  - U-pass restructured row-per-wave: wave wid reads rows wid*16+row16 over
//    all k (p = k-octet). Lane math lands on the IDENTICAL verified lUp unit
//    layout ((j*8+ks)*64+lane with j=wid, ks=p). s_u becomes lane-local
//    (full-k dot + quad shfl-reduce) -> lsuP scratch (4 KB), cross-wave
//    reduce, and the SECOND barrier all deleted. Epilogue reads lsu[col].
//  - VGPR: hb 64 + acc 36 + af/temps/addr ~20 ~= 120 <= 128 @ (512,4).
//  - Verified machinery unchanged (R1-R10): lUp unit layout, w1-column tile 8
//    for s_h-via-MFMA, f2bf for Up', pack8 casts for A-frag, C/D col=lane&15
//    row=quad*4+reg epilogue, XCD swizzle.

typedef __attribute__((ext_vector_type(8))) __bf16 bf16x8;
typedef __attribute__((ext_vector_type(8))) unsigned short ushort8v;
typedef __attribute__((ext_vector_type(4))) float f32x4;

__device__ __forceinline__ unsigned short f2bf(float f) {
    unsigned int u = __builtin_bit_cast(unsigned int, f);
    u += 0x7FFFu + ((u >> 16) & 1u);
    return (unsigned short)(u >> 16);
}

__device__ __forceinline__ bf16x8 pack8(const float4& a0, const float4& a1) {
    bf16x8 r;
    r[0] = (__bf16)a0.x; r[1] = (__bf16)a0.y; r[2] = (__bf16)a0.z; r[3] = (__bf16)a0.w;
    r[4] = (__bf16)a1.x; r[5] = (__bf16)a1.y; r[6] = (__bf16)a1.z; r[7] = (__bf16)a1.w;
    return r;
}

__global__ __launch_bounds__(512, 4)
void sim_fused(const float* __restrict__ H, const float* __restrict__ U,
               const float* __restrict__ w, float* __restrict__ out) {
    __shared__ ushort8v lUp[4608];   // 72 KB: tiles j=0..8, unit (j*8+ks)*64+lane
    __shared__ float    lsu[Jj];     // 512 B: s_u for this batch

    const int tid   = threadIdx.x;
    const int wid   = tid >> 6;
    const int lane  = tid & 63;
    const int row16 = lane & 15;
    const int quad  = lane >> 4;

    // Bijective XCD swizzle (assumed round-robin blockIdx->XCD): the 8 blocks
    // of batch b share one XCD's L2 for U[b].
    const int o     = blockIdx.x;
    const int b     = (o & 7) * 8 + ((o >> 3) & 7);
    const int mbase = (o >> 6) * 256;              // 8 m-tiles of 256 rows

    // ---- depth-8 H prefetch: issue the ENTIRE mt=0 A-tile as one burst ----
    // A-fragment layout: lane holds row mbase + mt*128 + wid*16 + row16,
    // k-slice ks covers floats [ks*32 + quad*8, +8).
    const float* Hbase = H + ((size_t)(b * Tt + mbase + wid * 16 + row16)) * Dd + quad * 8;
    float4 hb0[8], hb1[8];
#pragma unroll
    for (int p = 0; p < 8; ++p) {
        hb0[p] = *(const float4*)(Hbase + p * 32);
        hb1[p] = *(const float4*)(Hbase + p * 32 + 4);
    }

    // ---- U pass, row-per-wave: wave wid owns rows wid*16+row16, all k ----
    // Builds lUp[(wid*8+p)*64+lane] (identical bytes/layout as R10's build)
    // and a fully lane-local s_u partial.
    const float* Urow = U + ((size_t)(b * Jj + wid * 16 + row16)) * Dd + quad * 8;
    float sup = 0.f;
#pragma unroll
    for (int p = 0; p < 8; ++p) {
        const float4 u0 = *(const float4*)(Urow + p * 32);
        const float4 u1 = *(const float4*)(Urow + p * 32 + 4);
        const float* w3p = w + 2 * Dd + p * 32 + quad * 8;
        const float4 w30 = *(const float4*)(w3p);
        const float4 w31 = *(const float4*)(w3p + 4);
        const float* w2p = w + Dd + p * 32 + quad * 8;
        const float4 w20 = *(const float4*)(w2p);
        const float4 w21 = *(const float4*)(w2p + 4);
        ushort8v s;
        s[0] = f2bf(u0.x * w30.x); s[1] = f2bf(u0.y * w30.y);
        s[2] = f2bf(u0.z * w30.z); s[3] = f2bf(u0.w * w30.w);
        s[4] = f2bf(u1.x * w31.x); s[5] = f2bf(u1.y * w31.y);
        s[6] = f2bf(u1.z * w31.z); s[7] = f2bf(u1.w * w31.w);
        lUp[(wid * 8 + p) * 64 + lane] = s;
        sup += u0.x * w20.x + u0.y * w20.y + u0.z * w20.z + u0.w * w20.w
             + u1.x * w21.x + u1.y * w21.y + u1.z * w21.z + u1.w * w21.w;
    }
    {   // tile 8: w1-column, B[n][k] = (n==0) ? w1[k] : 0  (slice ks = wid)
        const int k0 = wid * 32 + quad * 8;
        const float4 w1a = *(const float4*)(w + k0);
        const float4 w1b = *(const float4*)(w + k0 + 4);
        const bool n0 = row16 == 0;
        ushort8v s;
        s[0] = n0 ? f2bf(w1a.x) : (unsigned short)0;
        s[1] = n0 ? f2bf(w1a.y) : (unsigned short)0;
        s[2] = n0 ? f2bf(w1a.z) : (unsigned short)0;
        s[3] = n0 ? f2bf(w1a.w) : (unsigned short)0;
        s[4] = n0 ? f2bf(w1b.x) : (unsigned short)0;
        s[5] = n0 ? f2bf(w1b.y) : (unsigned short)0;
        s[6] = n0 ? f2bf(w1b.z) : (unsigned short)0;
        s[7] = n0 ? f2bf(w1b.w) : (unsigned short)0;
        lUp[(8 * 8 + wid) * 64 + lane] = s;
    }
    // quad-reduce: lanes {r, r+16, r+32, r+48} hold the 4 k-quarters of row r
    sup += __shfl_xor(sup, 16);
    sup += __shfl_xor(sup, 32);
    if (lane < 16) lsu[wid * 16 + lane] = sup;    // quad==0, row16==lane

    f32x4 acc[9];
#pragma unroll
    for (int j = 0; j < 9; ++j) acc[j] = (f32x4){0.f, 0.f, 0.f, 0.f};

    __syncthreads();

    // ---- main loop: 2 m-tiles x 8 ks; slot == ks (full-tile registers) ----
#pragma unroll
    for (int mt = 0; mt < 2; ++mt) {
#pragma unroll
        for (int ks = 0; ks < 8; ++ks) {
            const float4 h0 = hb0[ks];
            const float4 h1 = hb1[ks];
            if (mt == 0) {   // static: refill this slot with mt=1's slice
                const float* np = Hbase + (size_t)(128 * Dd) + ks * 32;
                hb0[ks] = *(const float4*)(np);
                hb1[ks] = *(const float4*)(np + 4);
            }

            const bf16x8 af = pack8(h0, h1);
#pragma unroll
            for (int j = 0; j < 9; ++j) {
                const bf16x8 bf = __builtin_bit_cast(bf16x8, lUp[(j * 8 + ks) * 64 + lane]);
                acc[j] = __builtin_amdgcn_mfma_f32_16x16x32_bf16(af, bf, acc[j], 0, 0, 0);
            }
        }

        // epilogue for this m-tile
        // s_h for output row quad*4+rg lives in lane quad*16 (col 0) of acc[8]
        float shv[4];
#pragma unroll
        for (int rg = 0; rg < 4; ++rg)
            shv[rg] = __shfl(acc[8][rg], quad * 16);

        float* outW = out + ((size_t)(b * Tt + mbase + mt * 128 + wid * 16)) * Jj;
#pragma unroll
        for (int j = 0; j < 8; ++j) {
            const int col = j * 16 + row16;
            const float suv = lsu[col];
#pragma unroll
            for (int rg = 0; rg < 4; ++rg)
                outW[(size_t)(quad * 4 + rg) * Jj + col] = acc[j][rg] + shv[rg] + suv;
        }

        if (mt == 0) {
#pragma unroll
            for (int j = 0; j < 9; ++j) acc[j] = (f32x4){0.f, 0.f, 0.f, 0.f};
        }
    }
}

extern "C" void kernel_launch(void* const* d_in, const int* in_sizes, int n_in,
                              void* d_out, int out_size, void* d_ws, size_t ws_size,
                              hipStream_t stream) {
    const float* H = (const float*)d_in[0];
    const float* U = (const float*)d_in[1];
    const float* w = (const float*)d_in[2];
    float* out = (float*)d_out;
    (void)d_ws; (void)ws_size;

    sim_fused<<<Bb * 8, 512, 0, stream>>>(H, U, w, out);
}